// Round 1
// baseline (306.574 us; speedup 1.0000x reference)
//
#include <hip/hip_runtime.h>
#include <hip/hip_bf16.h>
#include <math.h>

typedef __attribute__((ext_vector_type(8))) short short8;
typedef __attribute__((ext_vector_type(16))) float f32x16;

#define DHEAD 64
#define KVB 32
#define QB 32

__device__ __forceinline__ unsigned pack2_bf16(float a, float b) {
  unsigned ua = __builtin_bit_cast(unsigned, a);
  unsigned ub = __builtin_bit_cast(unsigned, b);
  ua = (ua + 0x7fffu + ((ua >> 16) & 1u)) >> 16;
  ub = (ub + 0x7fffu + ((ub >> 16) & 1u)) >> 16;
  return (ua & 0xffffu) | (ub << 16);
}

union Frag { unsigned u[4]; short8 s; };

__global__ __launch_bounds__(64)
void fa_fwd(const float* __restrict__ Qg, const float* __restrict__ Kg,
            const float* __restrict__ Vg, const int* __restrict__ VL,
            float* __restrict__ Og, int Lq, int Lk) {
  const int lane = threadIdx.x & 63;
  const int l31  = lane & 31;
  const int hi   = lane >> 5;
  const int q0   = blockIdx.x * QB;
  const int b    = blockIdx.y;
  const int vl   = VL[b];

  const float* Qb = Qg + (size_t)b * Lq * DHEAD;
  const float* Kb = Kg + (size_t)b * Lk * DHEAD;
  const float* Vb = Vg + (size_t)b * Lk * DHEAD;

  // Q fragments (B operand of S^T = K * Q^T). Fold scale (1/8) * log2(e).
  const float cQ = 0.125f * 1.4426950408889634f;
  short8 qf[4];
  {
    const float* qrow = Qb + (size_t)(q0 + l31) * DHEAD + hi * 8;
    #pragma unroll
    for (int kk = 0; kk < 4; ++kk) {
      Frag fr;
      #pragma unroll
      for (int w = 0; w < 4; ++w)
        fr.u[w] = pack2_bf16(qrow[kk * 16 + 2 * w] * cQ,
                             qrow[kk * 16 + 2 * w + 1] * cQ);
      qf[kk] = fr.s;
    }
  }

  f32x16 o0 = {};  // O^T rows d=0..31  (col = query = lane&31)
  f32x16 o1 = {};  // O^T rows d=32..63
  float m = -INFINITY;
  float l = 0.0f;

  int nkb = (vl == 0) ? (Lk / KVB) : ((vl + KVB - 1) / KVB);
  if (nkb > Lk / KVB) nkb = Lk / KVB;
  const float MASKV = -1442695.04f;  // -1e6 * log2(e)

  for (int kb = 0; kb < nkb; ++kb) {
    const int key0 = kb * KVB;

    // ---- S^T tile (32 keys x 32 queries), scores already in log2 domain ----
    f32x16 s = {};
    {
      const float* krow = Kb + (size_t)(key0 + l31) * DHEAD + hi * 8;
      #pragma unroll
      for (int kk = 0; kk < 4; ++kk) {
        Frag fr;
        #pragma unroll
        for (int w = 0; w < 4; ++w)
          fr.u[w] = pack2_bf16(krow[kk * 16 + 2 * w], krow[kk * 16 + 2 * w + 1]);
        s = __builtin_amdgcn_mfma_f32_32x32x16_bf16(fr.s, qf[kk], s, 0, 0, 0);
      }
    }

    // ---- mask: key index >= valid_len gets -1e6 (log2 domain) ----
    if (key0 + KVB > vl) {
      #pragma unroll
      for (int r = 0; r < 16; ++r) {
        const int key = key0 + (r & 3) + 8 * (r >> 2) + 4 * hi;
        if (key >= vl) s[r] = MASKV;
      }
    }

    // ---- online softmax: lane holds 16 of the 32 keys for query lane&31 ----
    float tm = s[0];
    #pragma unroll
    for (int r = 1; r < 16; ++r) tm = fmaxf(tm, s[r]);
    tm = fmaxf(tm, __shfl_xor(tm, 32));
    const float mnew  = fmaxf(m, tm);
    const float alpha = exp2f(m - mnew);  // first iter: exp2(-inf) = 0
    float ps[16];
    float sum = 0.f;
    #pragma unroll
    for (int r = 0; r < 16; ++r) { ps[r] = exp2f(s[r] - mnew); sum += ps[r]; }
    sum += __shfl_xor(sum, 32);
    l = l * alpha + sum;
    m = mnew;
    #pragma unroll
    for (int r = 0; r < 16; ++r) { o0[r] *= alpha; o1[r] *= alpha; }

    // ---- pack P into B-operand frags of O^T += V^T * P^T ----
    // reg r of s/ps holds key (r&3) + 8*(r>>2) + 4*hi within the tile.
    short8 pf[2];
    #pragma unroll
    for (int kk = 0; kk < 2; ++kk) {
      const unsigned A0 = pack2_bf16(ps[8 * kk + 0], ps[8 * kk + 1]);
      const unsigned B0 = pack2_bf16(ps[8 * kk + 2], ps[8 * kk + 3]);
      const unsigned C0 = pack2_bf16(ps[8 * kk + 4], ps[8 * kk + 5]);
      const unsigned D0 = pack2_bf16(ps[8 * kk + 6], ps[8 * kk + 7]);
      const unsigned sA = (unsigned)__shfl_xor((int)A0, 32);
      const unsigned sB = (unsigned)__shfl_xor((int)B0, 32);
      const unsigned sC = (unsigned)__shfl_xor((int)C0, 32);
      const unsigned sD = (unsigned)__shfl_xor((int)D0, 32);
      Frag fr;
      fr.u[0] = hi ? sC : A0;
      fr.u[1] = hi ? sD : B0;
      fr.u[2] = hi ? C0 : sA;
      fr.u[3] = hi ? D0 : sB;
      pf[kk] = fr.s;
    }

    // ---- O^T += V^T * P^T  (A-frag: lane reads V[key][32c + lane&31]) ----
    #pragma unroll
    for (int kk = 0; kk < 2; ++kk) {
      const float* vrow = Vb + (size_t)(key0 + kk * 16 + hi * 8) * DHEAD + l31;
      Frag f0, f1;
      #pragma unroll
      for (int w = 0; w < 4; ++w) {
        f0.u[w] = pack2_bf16(vrow[(2 * w) * DHEAD],      vrow[(2 * w + 1) * DHEAD]);
        f1.u[w] = pack2_bf16(vrow[(2 * w) * DHEAD + 32], vrow[(2 * w + 1) * DHEAD + 32]);
      }
      o0 = __builtin_amdgcn_mfma_f32_32x32x16_bf16(f0.s, pf[kk], o0, 0, 0, 0);
      o1 = __builtin_amdgcn_mfma_f32_32x32x16_bf16(f1.s, pf[kk], o1, 0, 0, 0);
    }
  }

  // ---- epilogue: O[q][d] = O^T[d][q] / l ----
  const float rl = 1.0f / l;
  float* orow = Og + ((size_t)b * Lq + q0 + l31) * DHEAD;
  #pragma unroll
  for (int r = 0; r < 16; ++r) {
    const int dr = (r & 3) + 8 * (r >> 2) + 4 * hi;
    orow[dr]      = o0[r] * rl;
    orow[32 + dr] = o1[r] * rl;
  }
}

extern "C" void kernel_launch(void* const* d_in, const int* in_sizes, int n_in,
                              void* d_out, int out_size, void* d_ws, size_t ws_size,
                              hipStream_t stream) {
  const float* Q  = (const float*)d_in[0];
  const float* K  = (const float*)d_in[1];
  const float* V  = (const float*)d_in[2];
  const int*   VL = (const int*)d_in[3];
  float* O = (float*)d_out;

  const int B  = in_sizes[3];                  // 8
  const int Lq = in_sizes[0] / (B * DHEAD);    // 2048
  const int Lk = in_sizes[1] / (B * DHEAD);    // 2048

  dim3 grid(Lq / QB, B);
  fa_fwd<<<grid, 64, 0, stream>>>(Q, K, V, VL, O, Lq, Lk);
}

// Round 2
// 42.757 us; speedup vs baseline: 7.1701x; 7.1701x over previous
//
#include <hip/hip_runtime.h>
#include <hip/hip_bf16.h>
#include <math.h>

typedef __attribute__((ext_vector_type(8))) short short8;
typedef __attribute__((ext_vector_type(16))) float f32x16;

#define DHEAD 64
#define KVB 32
#define QB 32
#define NW 4   // waves per block = KV-split factor

__device__ __forceinline__ unsigned pack2_bf16(float a, float b) {
  unsigned ua = __builtin_bit_cast(unsigned, a);
  unsigned ub = __builtin_bit_cast(unsigned, b);
  ua = (ua + 0x7fffu + ((ua >> 16) & 1u)) >> 16;
  ub = (ub + 0x7fffu + ((ub >> 16) & 1u)) >> 16;
  return (ua & 0xffffu) | (ub << 16);
}

union Frag { unsigned u[4]; short8 s; };

__global__ __launch_bounds__(NW * 64)
void fa_fwd(const float* __restrict__ Qg, const float* __restrict__ Kg,
            const float* __restrict__ Vg, const int* __restrict__ VL,
            float* __restrict__ Og, int Lq, int Lk) {
  __shared__ float OLs[NW][QB][DHEAD + 1];   // +1 pad: conflict-free
  __shared__ float mLs[NW][QB];
  __shared__ float lLs[NW][QB];

  const int tid  = threadIdx.x;
  const int w    = tid >> 6;
  const int lane = tid & 63;
  const int l31  = lane & 31;
  const int hi   = lane >> 5;
  const int q0   = blockIdx.x * QB;
  const int b    = blockIdx.y;
  const int vl   = VL[b];

  const float* Qb = Qg + (size_t)b * Lq * DHEAD;
  const float* Kb = Kg + (size_t)b * Lk * DHEAD;
  const float* Vb = Vg + (size_t)b * Lk * DHEAD;

  // Q fragments (B operand of S^T = K * Q^T). Fold scale (1/8) * log2(e).
  const float cQ = 0.125f * 1.4426950408889634f;
  short8 qf[4];
  {
    const float* qrow = Qb + (size_t)(q0 + l31) * DHEAD + hi * 8;
    #pragma unroll
    for (int kk = 0; kk < 4; ++kk) {
      Frag fr;
      #pragma unroll
      for (int j = 0; j < 4; ++j)
        fr.u[j] = pack2_bf16(qrow[kk * 16 + 2 * j] * cQ,
                             qrow[kk * 16 + 2 * j + 1] * cQ);
      qf[kk] = fr.s;
    }
  }

  f32x16 o0 = {};  // O^T rows d=0..31  (col = query = lane&31)
  f32x16 o1 = {};  // O^T rows d=32..63
  float m = -INFINITY;
  float l = 0.0f;

  int nkb = (vl == 0) ? (Lk / KVB) : ((vl + KVB - 1) / KVB);
  if (nkb > Lk / KVB) nkb = Lk / KVB;
  const int nt = (nkb > w) ? ((nkb - w + NW - 1) / NW) : 0;  // my tile count

  const float MASKV = -1442695.04f;  // -1e6 * log2(e)

  float kraw[32], vraw[32];

  // prologue: issue first K-tile loads
  if (nt > 0) {
    const float* krow = Kb + (size_t)(w * KVB + l31) * DHEAD + hi * 8;
    #pragma unroll
    for (int kk = 0; kk < 4; ++kk)
      #pragma unroll
      for (int j = 0; j < 8; ++j) kraw[kk * 8 + j] = krow[kk * 16 + j];
  }

  for (int t = 0; t < nt; ++t) {
    const int key0 = (w + t * NW) * KVB;

    // pack K frags (first use of kraw -> waitcnt here)
    short8 kf[4];
    #pragma unroll
    for (int kk = 0; kk < 4; ++kk) {
      Frag fr;
      #pragma unroll
      for (int j = 0; j < 4; ++j)
        fr.u[j] = pack2_bf16(kraw[kk * 8 + 2 * j], kraw[kk * 8 + 2 * j + 1]);
      kf[kk] = fr.s;
    }

    // issue V loads for this tile (independent of S; covered by MFMA+softmax)
    #pragma unroll
    for (int kk = 0; kk < 2; ++kk) {
      const float* vrow = Vb + (size_t)(key0 + kk * 16 + hi * 8) * DHEAD + l31;
      #pragma unroll
      for (int j = 0; j < 8; ++j) {
        vraw[kk * 16 + j]     = vrow[j * DHEAD];
        vraw[kk * 16 + 8 + j] = vrow[j * DHEAD + 32];
      }
    }

    // S^T = K * Q^T (scores in log2 domain)
    f32x16 s = {};
    #pragma unroll
    for (int kk = 0; kk < 4; ++kk)
      s = __builtin_amdgcn_mfma_f32_32x32x16_bf16(kf[kk], qf[kk], s, 0, 0, 0);

    // prefetch next K tile (covered by softmax + PV)
    if (t + 1 < nt) {
      const float* krow = Kb + (size_t)(key0 + NW * KVB + l31) * DHEAD + hi * 8;
      #pragma unroll
      for (int kk = 0; kk < 4; ++kk)
        #pragma unroll
        for (int j = 0; j < 8; ++j) kraw[kk * 8 + j] = krow[kk * 16 + j];
    }

    // mask: key index >= valid_len gets -1e6 (log2 domain)
    if (key0 + KVB > vl) {
      #pragma unroll
      for (int r = 0; r < 16; ++r) {
        const int key = key0 + (r & 3) + 8 * (r >> 2) + 4 * hi;
        if (key >= vl) s[r] = MASKV;
      }
    }

    // online softmax (tree reductions)
    float t0 = fmaxf(s[0], s[1]),  t1 = fmaxf(s[2], s[3]);
    float t2 = fmaxf(s[4], s[5]),  t3 = fmaxf(s[6], s[7]);
    float t4 = fmaxf(s[8], s[9]),  t5 = fmaxf(s[10], s[11]);
    float t6 = fmaxf(s[12], s[13]), t7 = fmaxf(s[14], s[15]);
    t0 = fmaxf(t0, t1); t2 = fmaxf(t2, t3); t4 = fmaxf(t4, t5); t6 = fmaxf(t6, t7);
    t0 = fmaxf(t0, t2); t4 = fmaxf(t4, t6);
    float tm = fmaxf(t0, t4);
    tm = fmaxf(tm, __shfl_xor(tm, 32));
    const float mnew  = fmaxf(m, tm);
    const float alpha = exp2f(m - mnew);  // first iter: exp2(-inf) = 0
    #pragma unroll
    for (int r = 0; r < 16; ++r) s[r] = exp2f(s[r] - mnew);
    float u0 = s[0] + s[1],  u1 = s[2] + s[3];
    float u2 = s[4] + s[5],  u3 = s[6] + s[7];
    float u4 = s[8] + s[9],  u5 = s[10] + s[11];
    float u6 = s[12] + s[13], u7 = s[14] + s[15];
    u0 += u1; u2 += u3; u4 += u5; u6 += u7; u0 += u2; u4 += u6;
    float sum = u0 + u4;
    sum += __shfl_xor(sum, 32);
    l = l * alpha + sum;
    m = mnew;
    #pragma unroll
    for (int r = 0; r < 16; ++r) { o0[r] *= alpha; o1[r] *= alpha; }

    // pack P into B-operand frags of O^T += V^T * P^T
    short8 pf[2];
    #pragma unroll
    for (int kk = 0; kk < 2; ++kk) {
      const unsigned A0 = pack2_bf16(s[8 * kk + 0], s[8 * kk + 1]);
      const unsigned B0 = pack2_bf16(s[8 * kk + 2], s[8 * kk + 3]);
      const unsigned C0 = pack2_bf16(s[8 * kk + 4], s[8 * kk + 5]);
      const unsigned D0 = pack2_bf16(s[8 * kk + 6], s[8 * kk + 7]);
      const unsigned sA = (unsigned)__shfl_xor((int)A0, 32);
      const unsigned sB = (unsigned)__shfl_xor((int)B0, 32);
      const unsigned sC = (unsigned)__shfl_xor((int)C0, 32);
      const unsigned sD = (unsigned)__shfl_xor((int)D0, 32);
      Frag fr;
      fr.u[0] = hi ? sC : A0;
      fr.u[1] = hi ? sD : B0;
      fr.u[2] = hi ? C0 : sA;
      fr.u[3] = hi ? D0 : sB;
      pf[kk] = fr.s;
    }

    // O^T += V^T * P^T (pack vraw at use; waitcnt on V here)
    #pragma unroll
    for (int kk = 0; kk < 2; ++kk) {
      Frag f0, f1;
      #pragma unroll
      for (int j = 0; j < 4; ++j) {
        f0.u[j] = pack2_bf16(vraw[kk * 16 + 2 * j],     vraw[kk * 16 + 2 * j + 1]);
        f1.u[j] = pack2_bf16(vraw[kk * 16 + 8 + 2 * j], vraw[kk * 16 + 8 + 2 * j + 1]);
      }
      o0 = __builtin_amdgcn_mfma_f32_32x32x16_bf16(f0.s, pf[kk], o0, 0, 0, 0);
      o1 = __builtin_amdgcn_mfma_f32_32x32x16_bf16(f1.s, pf[kk], o1, 0, 0, 0);
    }
  }

  // publish partials: (m, l, O^T) per wave
  if (hi == 0) { mLs[w][l31] = m; lLs[w][l31] = l; }
  #pragma unroll
  for (int r = 0; r < 16; ++r) {
    const int dr = (r & 3) + 8 * (r >> 2) + 4 * hi;
    OLs[w][l31][dr]      = o0[r];
    OLs[w][l31][dr + 32] = o1[r];
  }
  __syncthreads();

  // combine NW partials per (q,d); coalesced global store
  for (int e = tid; e < QB * DHEAD; e += NW * 64) {
    const int q = e >> 6;
    const int d = e & 63;
    float M = mLs[0][q];
    #pragma unroll
    for (int ww = 1; ww < NW; ++ww) M = fmaxf(M, mLs[ww][q]);
    float L = 0.f, acc = 0.f;
    #pragma unroll
    for (int ww = 0; ww < NW; ++ww) {
      const float wgt = exp2f(mLs[ww][q] - M);  // idle wave: exp2(-inf)=0
      L   += lLs[ww][q] * wgt;
      acc += OLs[ww][q][d] * wgt;
    }
    Og[((size_t)b * Lq + q0 + q) * DHEAD + d] = acc / L;
  }
}

extern "C" void kernel_launch(void* const* d_in, const int* in_sizes, int n_in,
                              void* d_out, int out_size, void* d_ws, size_t ws_size,
                              hipStream_t stream) {
  const float* Q  = (const float*)d_in[0];
  const float* K  = (const float*)d_in[1];
  const float* V  = (const float*)d_in[2];
  const int*   VL = (const int*)d_in[3];
  float* O = (float*)d_out;

  const int B  = in_sizes[3];                  // 8
  const int Lq = in_sizes[0] / (B * DHEAD);    // 2048
  const int Lk = in_sizes[1] / (B * DHEAD);    // 2048

  dim3 grid(Lq / QB, B);
  fa_fwd<<<grid, NW * 64, 0, stream>>>(Q, K, V, VL, O, Lq, Lk);
}

// Round 3
// 40.809 us; speedup vs baseline: 7.5124x; 1.0477x over previous
//
#include <hip/hip_runtime.h>
#include <hip/hip_bf16.h>
#include <math.h>

typedef __attribute__((ext_vector_type(8))) short short8;
typedef __attribute__((ext_vector_type(16))) float f32x16;

#define DHEAD 64
#define KVB 32
#define QB 32
#define NW 8     // waves per block (KV-split factor) in the fast path
#define NWF 4    // waves per block in the fallback path

__device__ __forceinline__ unsigned pack2_bf16(float a, float b) {
  unsigned ua = __builtin_bit_cast(unsigned, a);
  unsigned ub = __builtin_bit_cast(unsigned, b);
  ua = (ua + 0x7fffu + ((ua >> 16) & 1u)) >> 16;
  ub = (ub + 0x7fffu + ((ub >> 16) & 1u)) >> 16;
  return (ua & 0xffffu) | (ub << 16);
}

union Frag { unsigned u[4]; short8 s; };

// ---------------- prep: K -> bf16 (same layout), V -> bf16 transposed ----------------
__global__ __launch_bounds__(256)
void prep_kv(const float* __restrict__ K, const float* __restrict__ V,
             unsigned short* __restrict__ Kh, unsigned short* __restrict__ VT, int Lk) {
  __shared__ float Vs[64][65];
  const int b = blockIdx.y;
  const int k0 = blockIdx.x * 64;
  const int tid = threadIdx.x;
  const size_t base = ((size_t)b * Lk + k0) * DHEAD;

  // K convert: 64 rows x 64 d = 4096 floats -> 512 short8 chunks
  for (int c = tid; c < 512; c += 256) {
    const float* src = K + base + (size_t)c * 8;
    Frag fr;
    #pragma unroll
    for (int j = 0; j < 4; ++j) fr.u[j] = pack2_bf16(src[2 * j], src[2 * j + 1]);
    *(short8*)(Kh + base + (size_t)c * 8) = fr.s;
  }
  // V tile -> LDS (coalesced)
  for (int e = tid; e < 4096; e += 256) Vs[e >> 6][e & 63] = V[base + e];
  __syncthreads();
  // VT[b][d][k] = V[b][k][d], written as packed u32 pairs along k (coalesced)
  unsigned* VT32 = (unsigned*)VT;
  for (int i = tid; i < 2048; i += 256) {
    const int d = i >> 5, jp = i & 31;
    VT32[(((size_t)b * DHEAD + d) * Lk + k0) / 2 + jp] =
        pack2_bf16(Vs[2 * jp][d], Vs[2 * jp + 1][d]);
  }
}

// ---------------- fast path: bf16 K/V pre-staged in ws ----------------
__global__ __launch_bounds__(NW * 64, 4)
void fa_fwd_pre(const float* __restrict__ Qg, const unsigned short* __restrict__ Khg,
                const unsigned short* __restrict__ VTg, const int* __restrict__ VL,
                float* __restrict__ Og, int Lq, int Lk) {
  __shared__ float OLs[NW][QB][DHEAD + 1];   // +1 pad: conflict-free strided writes
  __shared__ float mLs[NW][QB];
  __shared__ float lLs[NW][QB];

  const int tid  = threadIdx.x;
  const int w    = tid >> 6;
  const int lane = tid & 63;
  const int l31  = lane & 31;
  const int hi   = lane >> 5;
  const int q0   = blockIdx.x * QB;
  const int b    = blockIdx.y;
  const int vl   = VL[b];

  const float* Qb = Qg + (size_t)b * Lq * DHEAD;
  const unsigned short* Kb  = Khg + (size_t)b * Lk * DHEAD;
  const unsigned short* VTb = VTg + (size_t)b * DHEAD * Lk;

  // Q fragments (B operand of S^T = K * Q^T). Fold scale (1/8) * log2(e).
  const float cQ = 0.125f * 1.4426950408889634f;
  short8 qf[4];
  {
    const float* qrow = Qb + (size_t)(q0 + l31) * DHEAD + hi * 8;
    #pragma unroll
    for (int kk = 0; kk < 4; ++kk) {
      Frag fr;
      #pragma unroll
      for (int j = 0; j < 4; ++j)
        fr.u[j] = pack2_bf16(qrow[kk * 16 + 2 * j] * cQ,
                             qrow[kk * 16 + 2 * j + 1] * cQ);
      qf[kk] = fr.s;
    }
  }

  f32x16 o0 = {};  // O^T rows d=0..31  (col = query = lane&31)
  f32x16 o1 = {};  // O^T rows d=32..63
  float m = -INFINITY;
  float l = 0.0f;

  int nkb = (vl == 0) ? (Lk / KVB) : ((vl + KVB - 1) / KVB);
  if (nkb > Lk / KVB) nkb = Lk / KVB;
  const int nt = (nkb > w) ? ((nkb - w + NW - 1) / NW) : 0;

  const float MASKV = -1442695.04f;  // -1e6 * log2(e)

  for (int t = 0; t < nt; ++t) {
    const int key0 = (w + t * NW) * KVB;

    // K fragments: direct short8 loads (lane holds K[key0+l31][kk*16+hi*8 .. +7])
    short8 kf[4];
    #pragma unroll
    for (int kk = 0; kk < 4; ++kk)
      kf[kk] = *(const short8*)(Kb + (size_t)(key0 + l31) * DHEAD + kk * 16 + hi * 8);

    // V fragments: direct short8 loads from VT (lane: d=l31 / 32+l31, 8 consecutive keys)
    short8 vf0[2], vf1[2];
    #pragma unroll
    for (int kk = 0; kk < 2; ++kk) {
      const size_t ko = (size_t)key0 + kk * 16 + hi * 8;
      vf0[kk] = *(const short8*)(VTb + (size_t)l31 * Lk + ko);
      vf1[kk] = *(const short8*)(VTb + (size_t)(32 + l31) * Lk + ko);
    }

    // S^T = K * Q^T (scores in log2 domain)
    f32x16 s = {};
    #pragma unroll
    for (int kk = 0; kk < 4; ++kk)
      s = __builtin_amdgcn_mfma_f32_32x32x16_bf16(kf[kk], qf[kk], s, 0, 0, 0);

    // mask: key index >= valid_len gets -1e6 (log2 domain)
    if (key0 + KVB > vl) {
      #pragma unroll
      for (int r = 0; r < 16; ++r) {
        const int key = key0 + (r & 3) + 8 * (r >> 2) + 4 * hi;
        if (key >= vl) s[r] = MASKV;
      }
    }

    // online softmax (tree reductions)
    float t0 = fmaxf(s[0], s[1]),  t1 = fmaxf(s[2], s[3]);
    float t2 = fmaxf(s[4], s[5]),  t3 = fmaxf(s[6], s[7]);
    float t4 = fmaxf(s[8], s[9]),  t5 = fmaxf(s[10], s[11]);
    float t6 = fmaxf(s[12], s[13]), t7 = fmaxf(s[14], s[15]);
    t0 = fmaxf(t0, t1); t2 = fmaxf(t2, t3); t4 = fmaxf(t4, t5); t6 = fmaxf(t6, t7);
    t0 = fmaxf(t0, t2); t4 = fmaxf(t4, t6);
    float tm = fmaxf(t0, t4);
    tm = fmaxf(tm, __shfl_xor(tm, 32));
    const float mnew  = fmaxf(m, tm);
    const float alpha = exp2f(m - mnew);  // first iter: exp2(-inf) = 0
    #pragma unroll
    for (int r = 0; r < 16; ++r) s[r] = exp2f(s[r] - mnew);
    float u0 = s[0] + s[1],  u1 = s[2] + s[3];
    float u2 = s[4] + s[5],  u3 = s[6] + s[7];
    float u4 = s[8] + s[9],  u5 = s[10] + s[11];
    float u6 = s[12] + s[13], u7 = s[14] + s[15];
    u0 += u1; u2 += u3; u4 += u5; u6 += u7; u0 += u2; u4 += u6;
    float sum = u0 + u4;
    sum += __shfl_xor(sum, 32);
    l = l * alpha + sum;
    m = mnew;
    #pragma unroll
    for (int r = 0; r < 16; ++r) { o0[r] *= alpha; o1[r] *= alpha; }

    // pack P into B-operand frags of O^T += V^T * P^T
    short8 pf[2];
    #pragma unroll
    for (int kk = 0; kk < 2; ++kk) {
      const unsigned A0 = pack2_bf16(s[8 * kk + 0], s[8 * kk + 1]);
      const unsigned B0 = pack2_bf16(s[8 * kk + 2], s[8 * kk + 3]);
      const unsigned C0 = pack2_bf16(s[8 * kk + 4], s[8 * kk + 5]);
      const unsigned D0 = pack2_bf16(s[8 * kk + 6], s[8 * kk + 7]);
      const unsigned sA = (unsigned)__shfl_xor((int)A0, 32);
      const unsigned sB = (unsigned)__shfl_xor((int)B0, 32);
      const unsigned sC = (unsigned)__shfl_xor((int)C0, 32);
      const unsigned sD = (unsigned)__shfl_xor((int)D0, 32);
      Frag fr;
      fr.u[0] = hi ? sC : A0;
      fr.u[1] = hi ? sD : B0;
      fr.u[2] = hi ? C0 : sA;
      fr.u[3] = hi ? D0 : sB;
      pf[kk] = fr.s;
    }

    // O^T += V^T * P^T
    #pragma unroll
    for (int kk = 0; kk < 2; ++kk) {
      o0 = __builtin_amdgcn_mfma_f32_32x32x16_bf16(vf0[kk], pf[kk], o0, 0, 0, 0);
      o1 = __builtin_amdgcn_mfma_f32_32x32x16_bf16(vf1[kk], pf[kk], o1, 0, 0, 0);
    }
  }

  // publish partials: (m, l, O^T) per wave
  if (hi == 0) { mLs[w][l31] = m; lLs[w][l31] = l; }
  #pragma unroll
  for (int r = 0; r < 16; ++r) {
    const int dr = (r & 3) + 8 * (r >> 2) + 4 * hi;
    OLs[w][l31][dr]      = o0[r];
    OLs[w][l31][dr + 32] = o1[r];
  }
  __syncthreads();

  // combine NW partials per (q,d); coalesced global store
  for (int e = tid; e < QB * DHEAD; e += NW * 64) {
    const int q = e >> 6;
    const int d = e & 63;
    float M = mLs[0][q];
    #pragma unroll
    for (int ww = 1; ww < NW; ++ww) M = fmaxf(M, mLs[ww][q]);
    float L = 0.f, acc = 0.f;
    #pragma unroll
    for (int ww = 0; ww < NW; ++ww) {
      const float wgt = exp2f(mLs[ww][q] - M);  // idle wave: exp2(-inf)=0
      L   += lLs[ww][q] * wgt;
      acc += OLs[ww][q][d] * wgt;
    }
    Og[((size_t)b * Lq + q0 + q) * DHEAD + d] = acc / L;
  }
}

// ---------------- fallback (round-2 kernel, on-the-fly conversion) ----------------
__global__ __launch_bounds__(NWF * 64)
void fa_fwd(const float* __restrict__ Qg, const float* __restrict__ Kg,
            const float* __restrict__ Vg, const int* __restrict__ VL,
            float* __restrict__ Og, int Lq, int Lk) {
  __shared__ float OLs[NWF][QB][DHEAD + 1];
  __shared__ float mLs[NWF][QB];
  __shared__ float lLs[NWF][QB];

  const int tid  = threadIdx.x;
  const int w    = tid >> 6;
  const int lane = tid & 63;
  const int l31  = lane & 31;
  const int hi   = lane >> 5;
  const int q0   = blockIdx.x * QB;
  const int b    = blockIdx.y;
  const int vl   = VL[b];

  const float* Qb = Qg + (size_t)b * Lq * DHEAD;
  const float* Kb = Kg + (size_t)b * Lk * DHEAD;
  const float* Vb = Vg + (size_t)b * Lk * DHEAD;

  const float cQ = 0.125f * 1.4426950408889634f;
  short8 qf[4];
  {
    const float* qrow = Qb + (size_t)(q0 + l31) * DHEAD + hi * 8;
    #pragma unroll
    for (int kk = 0; kk < 4; ++kk) {
      Frag fr;
      #pragma unroll
      for (int j = 0; j < 4; ++j)
        fr.u[j] = pack2_bf16(qrow[kk * 16 + 2 * j] * cQ,
                             qrow[kk * 16 + 2 * j + 1] * cQ);
      qf[kk] = fr.s;
    }
  }

  f32x16 o0 = {};
  f32x16 o1 = {};
  float m = -INFINITY;
  float l = 0.0f;

  int nkb = (vl == 0) ? (Lk / KVB) : ((vl + KVB - 1) / KVB);
  if (nkb > Lk / KVB) nkb = Lk / KVB;
  const int nt = (nkb > w) ? ((nkb - w + NWF - 1) / NWF) : 0;

  const float MASKV = -1442695.04f;

  float kraw[32], vraw[32];

  if (nt > 0) {
    const float* krow = Kb + (size_t)(w * KVB + l31) * DHEAD + hi * 8;
    #pragma unroll
    for (int kk = 0; kk < 4; ++kk)
      #pragma unroll
      for (int j = 0; j < 8; ++j) kraw[kk * 8 + j] = krow[kk * 16 + j];
  }

  for (int t = 0; t < nt; ++t) {
    const int key0 = (w + t * NWF) * KVB;

    short8 kf[4];
    #pragma unroll
    for (int kk = 0; kk < 4; ++kk) {
      Frag fr;
      #pragma unroll
      for (int j = 0; j < 4; ++j)
        fr.u[j] = pack2_bf16(kraw[kk * 8 + 2 * j], kraw[kk * 8 + 2 * j + 1]);
      kf[kk] = fr.s;
    }

    #pragma unroll
    for (int kk = 0; kk < 2; ++kk) {
      const float* vrow = Vb + (size_t)(key0 + kk * 16 + hi * 8) * DHEAD + l31;
      #pragma unroll
      for (int j = 0; j < 8; ++j) {
        vraw[kk * 16 + j]     = vrow[j * DHEAD];
        vraw[kk * 16 + 8 + j] = vrow[j * DHEAD + 32];
      }
    }

    f32x16 s = {};
    #pragma unroll
    for (int kk = 0; kk < 4; ++kk)
      s = __builtin_amdgcn_mfma_f32_32x32x16_bf16(kf[kk], qf[kk], s, 0, 0, 0);

    if (t + 1 < nt) {
      const float* krow = Kb + (size_t)(key0 + NWF * KVB + l31) * DHEAD + hi * 8;
      #pragma unroll
      for (int kk = 0; kk < 4; ++kk)
        #pragma unroll
        for (int j = 0; j < 8; ++j) kraw[kk * 8 + j] = krow[kk * 16 + j];
    }

    if (key0 + KVB > vl) {
      #pragma unroll
      for (int r = 0; r < 16; ++r) {
        const int key = key0 + (r & 3) + 8 * (r >> 2) + 4 * hi;
        if (key >= vl) s[r] = MASKV;
      }
    }

    float t0 = fmaxf(s[0], s[1]),  t1 = fmaxf(s[2], s[3]);
    float t2 = fmaxf(s[4], s[5]),  t3 = fmaxf(s[6], s[7]);
    float t4 = fmaxf(s[8], s[9]),  t5 = fmaxf(s[10], s[11]);
    float t6 = fmaxf(s[12], s[13]), t7 = fmaxf(s[14], s[15]);
    t0 = fmaxf(t0, t1); t2 = fmaxf(t2, t3); t4 = fmaxf(t4, t5); t6 = fmaxf(t6, t7);
    t0 = fmaxf(t0, t2); t4 = fmaxf(t4, t6);
    float tm = fmaxf(t0, t4);
    tm = fmaxf(tm, __shfl_xor(tm, 32));
    const float mnew  = fmaxf(m, tm);
    const float alpha = exp2f(m - mnew);
    #pragma unroll
    for (int r = 0; r < 16; ++r) s[r] = exp2f(s[r] - mnew);
    float u0 = s[0] + s[1],  u1 = s[2] + s[3];
    float u2 = s[4] + s[5],  u3 = s[6] + s[7];
    float u4 = s[8] + s[9],  u5 = s[10] + s[11];
    float u6 = s[12] + s[13], u7 = s[14] + s[15];
    u0 += u1; u2 += u3; u4 += u5; u6 += u7; u0 += u2; u4 += u6;
    float sum = u0 + u4;
    sum += __shfl_xor(sum, 32);
    l = l * alpha + sum;
    m = mnew;
    #pragma unroll
    for (int r = 0; r < 16; ++r) { o0[r] *= alpha; o1[r] *= alpha; }

    short8 pf[2];
    #pragma unroll
    for (int kk = 0; kk < 2; ++kk) {
      const unsigned A0 = pack2_bf16(s[8 * kk + 0], s[8 * kk + 1]);
      const unsigned B0 = pack2_bf16(s[8 * kk + 2], s[8 * kk + 3]);
      const unsigned C0 = pack2_bf16(s[8 * kk + 4], s[8 * kk + 5]);
      const unsigned D0 = pack2_bf16(s[8 * kk + 6], s[8 * kk + 7]);
      const unsigned sA = (unsigned)__shfl_xor((int)A0, 32);
      const unsigned sB = (unsigned)__shfl_xor((int)B0, 32);
      const unsigned sC = (unsigned)__shfl_xor((int)C0, 32);
      const unsigned sD = (unsigned)__shfl_xor((int)D0, 32);
      Frag fr;
      fr.u[0] = hi ? sC : A0;
      fr.u[1] = hi ? sD : B0;
      fr.u[2] = hi ? C0 : sA;
      fr.u[3] = hi ? D0 : sB;
      pf[kk] = fr.s;
    }

    #pragma unroll
    for (int kk = 0; kk < 2; ++kk) {
      Frag f0, f1;
      #pragma unroll
      for (int j = 0; j < 4; ++j) {
        f0.u[j] = pack2_bf16(vraw[kk * 16 + 2 * j],     vraw[kk * 16 + 2 * j + 1]);
        f1.u[j] = pack2_bf16(vraw[kk * 16 + 8 + 2 * j], vraw[kk * 16 + 8 + 2 * j + 1]);
      }
      o0 = __builtin_amdgcn_mfma_f32_32x32x16_bf16(f0.s, pf[kk], o0, 0, 0, 0);
      o1 = __builtin_amdgcn_mfma_f32_32x32x16_bf16(f1.s, pf[kk], o1, 0, 0, 0);
    }
  }

  if (hi == 0) { mLs[w][l31] = m; lLs[w][l31] = l; }
  #pragma unroll
  for (int r = 0; r < 16; ++r) {
    const int dr = (r & 3) + 8 * (r >> 2) + 4 * hi;
    OLs[w][l31][dr]      = o0[r];
    OLs[w][l31][dr + 32] = o1[r];
  }
  __syncthreads();

  for (int e = tid; e < QB * DHEAD; e += NWF * 64) {
    const int q = e >> 6;
    const int d = e & 63;
    float M = mLs[0][q];
    #pragma unroll
    for (int ww = 1; ww < NWF; ++ww) M = fmaxf(M, mLs[ww][q]);
    float L = 0.f, acc = 0.f;
    #pragma unroll
    for (int ww = 0; ww < NWF; ++ww) {
      const float wgt = exp2f(mLs[ww][q] - M);
      L   += lLs[ww][q] * wgt;
      acc += OLs[ww][q][d] * wgt;
    }
    Og[((size_t)b * Lq + q0 + q) * DHEAD + d] = acc / L;
  }
}

extern "C" void kernel_launch(void* const* d_in, const int* in_sizes, int n_in,
                              void* d_out, int out_size, void* d_ws, size_t ws_size,
                              hipStream_t stream) {
  const float* Q  = (const float*)d_in[0];
  const float* K  = (const float*)d_in[1];
  const float* V  = (const float*)d_in[2];
  const int*   VL = (const int*)d_in[3];
  float* O = (float*)d_out;

  const int B  = in_sizes[3];                  // 8
  const int Lq = in_sizes[0] / (B * DHEAD);    // 2048
  const int Lk = in_sizes[1] / (B * DHEAD);    // 2048

  const size_t elems = (size_t)B * Lk * DHEAD;       // per tensor
  const size_t need  = elems * 2 * 2;                // Kh + VT in bf16

  if (ws_size >= need) {
    unsigned short* Kh = (unsigned short*)d_ws;
    unsigned short* VT = Kh + elems;
    dim3 pgrid(Lk / 64, B);
    prep_kv<<<pgrid, 256, 0, stream>>>(K, V, Kh, VT, Lk);
    dim3 grid(Lq / QB, B);
    fa_fwd_pre<<<grid, NW * 64, 0, stream>>>(Q, Kh, VT, VL, O, Lq, Lk);
  } else {
    dim3 grid(Lq / QB, B);
    fa_fwd<<<grid, NWF * 64, 0, stream>>>(Q, K, V, VL, O, Lq, Lk);
  }
}